// Round 8
// baseline (382.892 us; speedup 1.0000x reference)
//
#include <hip/hip_runtime.h>
#include <cstdint>

// ---------------------------------------------------------------------------
// R-FCN head on MI355X.  Round 12:
//  - fusedpool SOFTWARE-PIPELINED (the round-9 conv1 recipe): double-buffered
//    reg-staged A-loads (issue t+1's 9 loads before computing t), double-
//    buffered As/Bs, raw s_barrier + counted vmcnt(9) (never 0 mid-loop),
//    B-DMA issued after barrier (WAR-safe).  Round-11 counters: 4.8k cy/step
//    = serial {load->wait->fmaf->drain-barrier->MFMA->drain-barrier}; the two
//    __syncthreads drained vmcnt to 0 every step.  Same fmaf order -> P
//    bitwise identical.
//  - prep, conv1 ring pipeline, redfinal unchanged.  Round-11: 356.1us
//    (fusedpool 81, prep ~78, conv1 <79).  Predicted ~330us.
// ---------------------------------------------------------------------------

typedef __attribute__((ext_vector_type(8))) short short8;   // 8 bf16 (4 VGPRs)
typedef __attribute__((ext_vector_type(4))) short short4v;
typedef __attribute__((ext_vector_type(4))) float f32x4;

// workspace layout (bytes)
#define OFF_FEATT 0ull          // bf16 [4][4096][2048] = 67108864 (dead after conv1)
#define OFF_W1    67108864ull   // bf16 [1024][2048]    = 4194304  (dead after conv1)
#define OFF_X     71303168ull   // bf16 [4][4096][1024] = 33554432 -> ends 104857600
#define OFF_WC    104857600ull  // bf16 [128][49][1024] = 12845056 -> ends 117702656
#define OFF_DESC  117702656ull  // int  [1280][49][8]   = 2007040  -> ends 119709696
#define OFF_P     0ull          // bf16 [98][1280][112] = 28098560 (reuses featT region,
                                //   written only after conv1 has consumed featT)

__device__ __forceinline__ unsigned short f2bf(float f) {
  unsigned u = __float_as_uint(f);
  u += 0x7fffu + ((u >> 16) & 1u);        // round-to-nearest-even
  return (unsigned short)(u >> 16);
}
__device__ __forceinline__ float bf2f(unsigned short h) {
  return __uint_as_float(((unsigned)h) << 16);
}

// swizzle low-6-bits of a k index: 16B group g (bits 3..5) -> g ^ key
__device__ __forceinline__ int swz6(int k6, int key) {
  return ((((k6 >> 3) & 7) ^ key) << 3) | (k6 & 7);
}

__device__ __forceinline__ void gload16(const void* g, void* l) {
  __builtin_amdgcn_global_load_lds((const __attribute__((address_space(1))) void*)g,
                                   (__attribute__((address_space(3))) void*)l, 16, 0, 0);
}

// --- merged preprocessing: cvt_w1 | cvt_wcomb | desc | tpose ---------------
// grid.x = 2048 + 6272 + 245 + 4096 = 12661 blocks of 256.
__global__ __launch_bounds__(256) void k_prep(const float* __restrict__ w_conv1,
                                              const float* __restrict__ wcls,
                                              const float* __restrict__ wbbox,
                                              const float* __restrict__ rois,
                                              const float* __restrict__ base_feat,
                                              unsigned short* __restrict__ w1b,
                                              unsigned short* __restrict__ Wc,
                                              int* __restrict__ desc,
                                              unsigned short* __restrict__ featT) {
  __shared__ float tile2[2][64][65];        // used by tpose branch only
  int bid = blockIdx.x;
  if (bid < 2048) {
    // ---- cvt_w1: fp32 [1024][2048] -> bf16 swizzled ----
    int t = bid * 256 + threadIdx.x;
    long e = (long)t * 4;
    int o = (int)(e >> 11), k = (int)(e & 2047);
    float4 q = *(const float4*)(w_conv1 + e);
    short4v s = {(short)f2bf(q.x), (short)f2bf(q.y), (short)f2bf(q.z), (short)f2bf(q.w)};
    int kp = (k & ~63) | swz6(k & 63, o & 7);
    *(short4v*)(w1b + (size_t)o * 2048 + kp) = s;
  } else if (bid < 8320) {
    // ---- cvt_wcomb: Wc[c][ij][k]; c<21 cls, c<105 bbox, else 0 ----
    int t = (bid - 2048) * 256 + threadIdx.x;
    size_t e = (size_t)t * 4;
    int c = (int)(e / 50176);
    int rem = (int)(e - (size_t)c * 50176);
    int ij = rem >> 10, k = rem & 1023;
    float4 q = make_float4(0.f, 0.f, 0.f, 0.f);
    if (c < 21)       q = *(const float4*)(wcls + (size_t)(c * 49 + ij) * 1024 + k);
    else if (c < 105) q = *(const float4*)(wbbox + (size_t)((c - 21) * 49 + ij) * 1024 + k);
    short4v s = {(short)f2bf(q.x), (short)f2bf(q.y), (short)f2bf(q.z), (short)f2bf(q.w)};
    int kp = (k & ~63) | swz6(k & 63, c & 7);
    *(short4v*)(Wc + ((size_t)(c * 49 + ij) * 1024 + kp)) = s;
  } else if (bid < 8565) {
    // ---- desc: per-(roi,bin) descriptors (fp32 ops mirror reference) ----
    int t = (bid - 8320) * 256 + threadIdx.x;
    if (t >= 1280 * 49) return;
    int roi = t / 49, ij = t - roi * 49;
    int* d = desc + (size_t)t * 8;
    if (roi >= 1200) { d[0] = 0; d[1] = 0; d[2] = 0; d[3] = 0; d[4] = 0; ((float*)d)[5] = 0.f; return; }
    const float* r = rois + (size_t)roi * 5;
    int b = (int)r[0];
    float x1 = __fmul_rn(floorf(__fadd_rn(r[1], 0.5f)), 0.0625f);
    float y1 = __fmul_rn(floorf(__fadd_rn(r[2], 0.5f)), 0.0625f);
    float x2 = __fmul_rn(floorf(__fadd_rn(__fadd_rn(r[3], 1.0f), 0.5f)), 0.0625f);
    float y2 = __fmul_rn(floorf(__fadd_rn(__fadd_rn(r[4], 1.0f), 0.5f)), 0.0625f);
    float bw = __fdiv_rn(fmaxf(__fsub_rn(x2, x1), 0.1f), 7.0f);
    float bh = __fdiv_rn(fmaxf(__fsub_rn(y2, y1), 0.1f), 7.0f);
    int i = ij / 7, j = ij - (ij / 7) * 7;
    float fi = (float)i, fj = (float)j;
    int hs = (int)fminf(fmaxf(floorf(__fadd_rn(__fmul_rn(fi, bh), y1)), 0.f), 64.f);
    int he = (int)fminf(fmaxf(ceilf(__fadd_rn(__fmul_rn(__fadd_rn(fi, 1.f), bh), y1)), 0.f), 64.f);
    int wsx = (int)fminf(fmaxf(floorf(__fadd_rn(__fmul_rn(fj, bw), x1)), 0.f), 64.f);
    int we = (int)fminf(fmaxf(ceilf(__fadd_rn(__fmul_rn(__fadd_rn(fj, 1.f), bw), x1)), 0.f), 64.f);
    int dh = max(he - hs, 0), dw = max(we - wsx, 0);
    float inv = (dh * dw > 0) ? 1.0f / (float)(dh * dw) : 0.f;
    d[0] = b; d[1] = hs; d[2] = he; d[3] = wsx; d[4] = we;
    ((float*)d)[5] = inv;
  } else {
    // ---- tpose: base_feat [b][c][s] fp32 -> featT [b][s][c] bf16 swizzled ----
    // two 64x64 s-tiles per block; 8 float4 loads in flight before barrier.
    int t = bid - 8565;                 // 0..4095
    int s0 = (t & 31) * 128;
    int c0 = ((t >> 5) & 31) * 64;
    int b = t >> 10;
    int tx4 = (threadIdx.x & 15) * 4;   // s offset (float4)
    int cl0 = threadIdx.x >> 4;         // 16 c-rows per pass
    const float* sp = base_feat + ((size_t)b * 2048 + c0) * 4096 + s0;
    float4 q[8];
#pragma unroll
    for (int tt = 0; tt < 2; tt++)
#pragma unroll
      for (int i = 0; i < 4; i++) {
        int cl = i * 16 + cl0;
        q[tt * 4 + i] = *(const float4*)(sp + (size_t)cl * 4096 + tt * 64 + tx4);
      }
#pragma unroll
    for (int tt = 0; tt < 2; tt++)
#pragma unroll
      for (int i = 0; i < 4; i++)
        *(float4*)&tile2[tt][i * 16 + cl0][tx4] = q[tt * 4 + i];
    __syncthreads();
    int c8 = (threadIdx.x & 7) * 8;     // 8-channel group (one 16B swizzle unit)
    int sy = threadIdx.x >> 3;          // 0..31 spatial rows per pass
#pragma unroll
    for (int tt = 0; tt < 2; tt++) {
      unsigned short* dp = featT + ((size_t)b * 4096 + s0 + tt * 64) * 2048 + c0;
#pragma unroll
      for (int i = 0; i < 2; i++) {
        int sl = i * 32 + sy;
        int key = sl & 7;
        short8 v = {(short)f2bf(tile2[tt][c8 + 0][sl]), (short)f2bf(tile2[tt][c8 + 1][sl]),
                    (short)f2bf(tile2[tt][c8 + 2][sl]), (short)f2bf(tile2[tt][c8 + 3][sl]),
                    (short)f2bf(tile2[tt][c8 + 4][sl]), (short)f2bf(tile2[tt][c8 + 5][sl]),
                    (short)f2bf(tile2[tt][c8 + 6][sl]), (short)f2bf(tile2[tt][c8 + 7][sl])};
        *(short8*)(dp + (size_t)sl * 2048 + ((((c8 >> 3) ^ key) << 3))) = v;  // 16B store
      }
    }
  }
}

// --- conv1: X[s][o] = relu(sum_k featT[s][k] * w1[o][k]), bf16 out ---------
// 256x256 tile, BK=64, 8 waves (2M x 4N), 9-slot half-tile LDS ring.
__global__ __launch_bounds__(512, 2) void k_gemm_conv1(const short* __restrict__ A,
                                                       const short* __restrict__ Bw,
                                                       unsigned short* __restrict__ X) {
  __shared__ short lds[9 * 8192];   // 9 x 16KB = 144KB ring
  int mt = blockIdx.x, nt = blockIdx.y;
  int tid = threadIdx.x, lane = tid & 63, wave = tid >> 6;
  int wm = wave >> 2, wn = wave & 3;          // 2 x 4 wave grid (128x64 each)

  const short* Ab = A + (size_t)mt * 256 * 2048;
  const short* Bb = Bw + (size_t)nt * 256 * 2048;

  f32x4 acc[8][4];
#pragma unroll
  for (int i = 0; i < 8; i++)
#pragma unroll
    for (int j = 0; j < 4; j++) acc[i][j] = (f32x4){0.f, 0.f, 0.f, 0.f};

  int sr = tid >> 3;                 // staging row 0..63
  int sc = (tid & 7) * 8;            // staging k elem
  auto stage_half = [&](int h) {
    if (h >= 128) return;
    int kind = h & 3, tl = h >> 2, slot = h % 9;
    const short* src = ((kind & 2) ? Bb : Ab)
                     + (size_t)((kind & 1) * 128 + sr) * 2048 + tl * 64 + sc;
    char* dst = (char*)lds + slot * 16384 + tid * 16;
    gload16(src, dst);
    gload16(src + (size_t)64 * 2048, dst + 8192);
  };

  // prologue: stage halves 0..4 (tile 0 fully + Ah0 of tile 1)
#pragma unroll
  for (int h = 0; h < 5; h++) stage_half(h);

  int la15 = lane & 15;
  int key = lane & 7;
  int ko0 = (((lane >> 4)) ^ key) << 3;        // kt=0 fragment k-offset (elems)
  int ko1 = ((4 | (lane >> 4)) ^ key) << 3;    // kt=1
  int bro = (wn & 1) * 64;                     // B local row offset within half

  for (int t = 0; t < 32; ++t) {
    if (t < 31) asm volatile("s_waitcnt vmcnt(2)" ::: "memory");
    else        asm volatile("s_waitcnt vmcnt(0)" ::: "memory");
    __builtin_amdgcn_s_barrier();
    __builtin_amdgcn_sched_barrier(0);
    const short* Asl = lds + (size_t)((4 * t + wm) % 9) * 8192;
    const short* Bsl = lds + (size_t)((4 * t + 2 + (wn >> 1)) % 9) * 8192;
    short8 af[4], bf[4];

    // ---- phase 0: mh=0, kt=0 ----
    stage_half(4 * t + 5);
#pragma unroll
    for (int j = 0; j < 4; j++)
      bf[j] = *(const short8*)(Bsl + (bro + j * 16 + la15) * 64 + ko0);
#pragma unroll
    for (int i = 0; i < 4; i++)
      af[i] = *(const short8*)(Asl + (i * 16 + la15) * 64 + ko0);
    __builtin_amdgcn_s_setprio(1);
#pragma unroll
    for (int i = 0; i < 4; i++)
#pragma unroll
      for (int j = 0; j < 4; j++)
        acc[i][j] = __builtin_amdgcn_mfma_f32_16x16x32_bf16(af[i], bf[j], acc[i][j], 0, 0, 0);
    __builtin_amdgcn_s_setprio(0);

    // ---- phase 1: mh=1, kt=0 ----
    stage_half(4 * t + 6);
#pragma unroll
    for (int i = 0; i < 4; i++)
      af[i] = *(const short8*)(Asl + (64 + i * 16 + la15) * 64 + ko0);
    __builtin_amdgcn_s_setprio(1);
#pragma unroll
    for (int i = 0; i < 4; i++)
#pragma unroll
      for (int j = 0; j < 4; j++)
        acc[4 + i][j] = __builtin_amdgcn_mfma_f32_16x16x32_bf16(af[i], bf[j], acc[4 + i][j], 0, 0, 0);
    __builtin_amdgcn_s_setprio(0);

    // ---- phase 2: mh=0, kt=1 ----
    stage_half(4 * t + 7);
#pragma unroll
    for (int j = 0; j < 4; j++)
      bf[j] = *(const short8*)(Bsl + (bro + j * 16 + la15) * 64 + ko1);
#pragma unroll
    for (int i = 0; i < 4; i++)
      af[i] = *(const short8*)(Asl + (i * 16 + la15) * 64 + ko1);
    __builtin_amdgcn_s_setprio(1);
#pragma unroll
    for (int i = 0; i < 4; i++)
#pragma unroll
      for (int j = 0; j < 4; j++)
        acc[i][j] = __builtin_amdgcn_mfma_f32_16x16x32_bf16(af[i], bf[j], acc[i][j], 0, 0, 0);
    __builtin_amdgcn_s_setprio(0);

    // ---- phase 3: mh=1, kt=1 ----
    stage_half(4 * t + 8);
#pragma unroll
    for (int i = 0; i < 4; i++)
      af[i] = *(const short8*)(Asl + (64 + i * 16 + la15) * 64 + ko1);
    __builtin_amdgcn_s_setprio(1);
#pragma unroll
    for (int i = 0; i < 4; i++)
#pragma unroll
      for (int j = 0; j < 4; j++)
        acc[4 + i][j] = __builtin_amdgcn_mfma_f32_16x16x32_bf16(af[i], bf[j], acc[4 + i][j], 0, 0, 0);
    __builtin_amdgcn_s_setprio(0);
  }

  unsigned short* Xo = X + ((size_t)(mt * 256 + wm * 128)) * 1024 + nt * 256 + wn * 64;
#pragma unroll
  for (int ii = 0; ii < 8; ii++)
#pragma unroll
    for (int j = 0; j < 4; j++) {
      int row = ii * 16 + (lane >> 4) * 4;
      int col = j * 16 + la15;
#pragma unroll
      for (int r = 0; r < 4; r++)
        Xo[(size_t)(row + r) * 1024 + col] = f2bf(fmaxf(acc[ii][j][r], 0.f));
    }
}

// --- fused pool-GEMM (k-split, software-pipelined) -------------------------
// P[kh*49+ij][roi][c] = sum_{k in half kh} mean_bin(X)[roi][ij][k] * Wc[c][ij][k]
// 512 threads; thread (roi, k8) builds A; 9 clamped loads double-buffered
// (issue t+1 before computing t); As/Bs double-buffered; counted vmcnt(9).
__global__ __launch_bounds__(512) void k_fusedpool(const unsigned short* __restrict__ Xb,
                                                   const int* __restrict__ desc,
                                                   const unsigned short* __restrict__ Wc,
                                                   unsigned short* __restrict__ P,
                                                   int nroi) {
  int mt = blockIdx.x;   // 64-roi tile
  int ij = blockIdx.y;   // 0..48
  int kh = blockIdx.z;   // k-half 0..1
  __shared__ short As[2 * 4096];   // 2 x [64 roi][64 k] bf16 (swizzled image)
  __shared__ short Bs[2 * 8192];   // 2 x [128 c][64 k]
  __shared__ int dsc[64][4];       // cellstart, dh, dw, inv-bits
  int tid = threadIdx.x, lane = tid & 63, wave = tid >> 6;

  if (tid < 64) {
    const int* d = desc + ((size_t)(mt * 64 + tid) * 49 + ij) * 8;
    int b = d[0], hs = d[1], he = d[2], wsx = d[3], we = d[4];
    dsc[tid][0] = (b * 64 + hs) * 64 + wsx;   // start cell index
    dsc[tid][1] = max(he - hs, 0);            // dh
    dsc[tid][2] = max(we - wsx, 0);           // dw
    dsc[tid][3] = d[5];                       // inv (float bits)
  }
  __syncthreads();

  f32x4 acc[4];
#pragma unroll
  for (int i = 0; i < 4; i++) acc[i] = (f32x4){0.f, 0.f, 0.f, 0.f};

  const unsigned short* Bb = Wc + (size_t)ij * 1024;
  int lr = lane >> 3, lc = (lane & 7) * 8;   // B staging lane mapping
  int key = lane & 7;
  int la15 = lane & 15;
  int r64 = tid >> 3;         // 0..63: this thread's roi
  int k8 = tid & 7;           // 8-bf16 k-group
  int cs = dsc[r64][0], dh = dsc[r64][1], dw = dsc[r64][2];
  float inv = __int_as_float(dsc[r64][3]);
  int aswz = r64 * 64 + ((k8 ^ (r64 & 7)) << 3);
  int kbeg = kh * 512;

  // loop-invariant per-cell masks + element offsets (static after unroll)
  float mm[9];
  int off[9];
#pragma unroll
  for (int hh = 0; hh < 3; hh++)
#pragma unroll
    for (int ww = 0; ww < 3; ww++) {
      mm[hh * 3 + ww] = ((hh < dh) && (ww < dw)) ? inv : 0.f;
      off[hh * 3 + ww] = (((hh < dh) ? hh : 0) * 64 + ((ww < dw) ? ww : 0)) * 1024;
    }
  const unsigned short* xbase = Xb + (size_t)cs * 1024 + kbeg + k8 * 8;

  auto load9 = [&](short8* v, int kstep) {
    const unsigned short* p = xbase + kstep * 64;
#pragma unroll
    for (int c = 0; c < 9; c++) v[c] = *(const short8*)(p + off[c]);
  };
  auto issueB = [&](int slot, int kstep) {
    int row = wave * 8 + lr;
    const unsigned short* src = Bb + (size_t)row * (49 * 1024) + kbeg + kstep * 64 + lc;
    char* dst = (char*)Bs + slot * 16384 + wave * 1024;
    gload16(src, dst);
    gload16(src + (size_t)64 * (49 * 1024), dst + 8192);
  };
  auto avg_store = [&](short8* v, int slot) {
    float a0 = 0.f, a1 = 0.f, a2 = 0.f, a3 = 0.f;
    float a4 = 0.f, a5 = 0.f, a6 = 0.f, a7 = 0.f;
#pragma unroll
    for (int c = 0; c < 9; c++) {
      float m = mm[c];
      short8 vv = v[c];
      a0 = fmaf(m, bf2f((unsigned short)vv[0]), a0);
      a1 = fmaf(m, bf2f((unsigned short)vv[1]), a1);
      a2 = fmaf(m, bf2f((unsigned short)vv[2]), a2);
      a3 = fmaf(m, bf2f((unsigned short)vv[3]), a3);
      a4 = fmaf(m, bf2f((unsigned short)vv[4]), a4);
      a5 = fmaf(m, bf2f((unsigned short)vv[5]), a5);
      a6 = fmaf(m, bf2f((unsigned short)vv[6]), a6);
      a7 = fmaf(m, bf2f((unsigned short)vv[7]), a7);
    }
    short8 o = {(short)f2bf(a0), (short)f2bf(a1), (short)f2bf(a2), (short)f2bf(a3),
                (short)f2bf(a4), (short)f2bf(a5), (short)f2bf(a6), (short)f2bf(a7)};
    *(short8*)(As + slot * 4096 + aswz) = o;
  };

  short8 vA[9], vB[9];
  load9(vA, 0);
  issueB(0, 0);

#pragma unroll
  for (int t = 0; t < 8; t++) {
    short8* cur = (t & 1) ? vB : vA;
    short8* nxt = (t & 1) ? vA : vB;
    if (t < 7) {
      load9(nxt, t + 1);
      asm volatile("s_waitcnt vmcnt(9)" ::: "memory");   // t's 9 A + 2 B done
    } else {
      asm volatile("s_waitcnt vmcnt(0)" ::: "memory");
    }
    __builtin_amdgcn_s_barrier();                        // Bs[t&1] visible to all
    if (t < 7) issueB((t + 1) & 1, t + 1);               // safe: after barrier
    avg_store(cur, t & 1);
    asm volatile("s_waitcnt lgkmcnt(0)" ::: "memory");
    __builtin_amdgcn_s_barrier();                        // As[t&1] visible
    const short* Asl = As + (t & 1) * 4096;
    const short* Bsl = Bs + (t & 1) * 8192;
#pragma unroll
    for (int kt = 0; kt < 2; kt++) {
      int ko = (((kt << 2) | (lane >> 4)) ^ key) << 3;
      short8 bfr = *(const short8*)(Bsl + (wave * 16 + la15) * 64 + ko);
      short8 af[4];
#pragma unroll
      for (int i = 0; i < 4; i++)
        af[i] = *(const short8*)(Asl + (i * 16 + la15) * 64 + ko);
      __builtin_amdgcn_s_setprio(1);
#pragma unroll
      for (int i = 0; i < 4; i++)
        acc[i] = __builtin_amdgcn_mfma_f32_16x16x32_bf16(af[i], bfr, acc[i], 0, 0, 0);
      __builtin_amdgcn_s_setprio(0);
    }
  }
  // store partials P[kh*49+ij][nroi][112] bf16 (c>=112 dropped; only c<105 used)
  unsigned short* Pb = P + (size_t)(kh * 49 + ij) * nroi * 112;
  int cc = wave * 16 + la15;
  if (cc < 112) {
#pragma unroll
    for (int i = 0; i < 4; i++) {
      int rbase = mt * 64 + i * 16 + (lane >> 4) * 4;
#pragma unroll
      for (int r = 0; r < 4; r++)
        Pb[(size_t)(rbase + r) * 112 + cc] = f2bf(acc[i][r]);
    }
  }
}

// --- reduce 98 partials -> score -> softmax/bbox out (one block per roi) ---
__global__ __launch_bounds__(128) void k_redfinal(const unsigned short* __restrict__ P,
                                                  float* __restrict__ out, int nroi) {
  int roi = blockIdx.x;        // 0..1199
  int c = threadIdx.x;         // 0..127
  __shared__ float sc[112];
  __shared__ float es[32];
  if (c < 112) {
    const unsigned short* p = P + (size_t)roi * 112 + c;
    float s = 0.f;
#pragma unroll 7
    for (int ij = 0; ij < 98; ij++) s += bf2f(p[(size_t)ij * nroi * 112]);
    sc[c] = s * (1.f / 49.f);
  }
  __syncthreads();
  if (c < 21) {
    float mx = -1e30f;
#pragma unroll
    for (int k = 0; k < 21; k++) mx = fmaxf(mx, sc[k]);
    es[c] = expf(sc[c] - mx);
  }
  __syncthreads();
  if (c < 21) {
    float sum = 0.f;
#pragma unroll
    for (int k = 0; k < 21; k++) sum += es[k];
    float rs = 1.f / sum;
    out[(size_t)roi * 21 + c] = es[c] * rs;
  }
  if (c >= 21 && c < 105) {
    out[25200 + (size_t)roi * 84 + (c - 21)] = sc[c];
  }
}

extern "C" void kernel_launch(void* const* d_in, const int* in_sizes, int n_in,
                              void* d_out, int out_size, void* d_ws, size_t ws_size,
                              hipStream_t stream) {
  const float* base_feat = (const float*)d_in[0];
  const float* rois      = (const float*)d_in[1];
  const float* w_conv1   = (const float*)d_in[2];
  const float* w_cls     = (const float*)d_in[3];
  const float* w_bbox    = (const float*)d_in[4];
  float* out = (float*)d_out;
  char* ws = (char*)d_ws;

  unsigned short* featT = (unsigned short*)(ws + OFF_FEATT);
  unsigned short* w1b   = (unsigned short*)(ws + OFF_W1);
  unsigned short* X     = (unsigned short*)(ws + OFF_X);
  unsigned short* Wc    = (unsigned short*)(ws + OFF_WC);
  int*            desc  = (int*)(ws + OFF_DESC);
  unsigned short* P     = (unsigned short*)(ws + OFF_P);

  k_prep<<<12661, 256, 0, stream>>>(w_conv1, w_cls, w_bbox, rois, base_feat,
                                    w1b, Wc, desc, featT);
  k_gemm_conv1<<<dim3(64, 4), 512, 0, stream>>>((const short*)featT, (const short*)w1b, X);
  k_fusedpool<<<dim3(20, 49, 2), 512, 0, stream>>>(X, desc, Wc, P, 1280);
  k_redfinal<<<1200, 128, 0, stream>>>(P, out, 1280);
}

// Round 9
// 378.292 us; speedup vs baseline: 1.0122x; 1.0122x over previous
//
#include <hip/hip_runtime.h>
#include <cstdint>

// ---------------------------------------------------------------------------
// R-FCN head on MI355X.  Round 13:
//  - REVERT fusedpool to the round-8 structure (256t, 2-pass A-build, 3x3
//    masked batch loads, plain syncthreads) -- measured 77.4us/occ 33%.
//    Round-12's reg-dbuf pipeline cut occupancy to 20% (VGPR 76, LDS 49KB)
//    and regressed to 107us: fusedpool is TLP-bound, not pipeline-bound.
//  - NEW: XCD-locality grid swizzle. 98 blocks sharing an mt (same 64 rois,
//    overlapping X rows) now map to blockIdx with equal b%8 -> same XCD ->
//    X bin-reads hit that XCD's L2 (~200cy) instead of L3/HBM (~500-900cy).
//    FETCH was 143-170MB vs 46MB compulsory (cross-XCD re-fetch).
//    Decode-only change -> bitwise-identical P.
//  - prep, conv1 ring pipeline, redfinal unchanged.  Round-12: 382.9us.
//  Predicted ~345us; absmax exactly 0.0006942749.
// ---------------------------------------------------------------------------

typedef __attribute__((ext_vector_type(8))) short short8;   // 8 bf16 (4 VGPRs)
typedef __attribute__((ext_vector_type(4))) short short4v;
typedef __attribute__((ext_vector_type(4))) float f32x4;

// workspace layout (bytes)
#define OFF_FEATT 0ull          // bf16 [4][4096][2048] = 67108864 (dead after conv1)
#define OFF_W1    67108864ull   // bf16 [1024][2048]    = 4194304  (dead after conv1)
#define OFF_X     71303168ull   // bf16 [4][4096][1024] = 33554432 -> ends 104857600
#define OFF_WC    104857600ull  // bf16 [128][49][1024] = 12845056 -> ends 117702656
#define OFF_DESC  117702656ull  // int  [1280][49][8]   = 2007040  -> ends 119709696
#define OFF_P     0ull          // bf16 [98][1280][112] = 28098560 (reuses featT region,
                                //   written only after conv1 has consumed featT)

__device__ __forceinline__ unsigned short f2bf(float f) {
  unsigned u = __float_as_uint(f);
  u += 0x7fffu + ((u >> 16) & 1u);        // round-to-nearest-even
  return (unsigned short)(u >> 16);
}
__device__ __forceinline__ float bf2f(unsigned short h) {
  return __uint_as_float(((unsigned)h) << 16);
}

// swizzle low-6-bits of a k index: 16B group g (bits 3..5) -> g ^ key
__device__ __forceinline__ int swz6(int k6, int key) {
  return ((((k6 >> 3) & 7) ^ key) << 3) | (k6 & 7);
}

__device__ __forceinline__ void gload16(const void* g, void* l) {
  __builtin_amdgcn_global_load_lds((const __attribute__((address_space(1))) void*)g,
                                   (__attribute__((address_space(3))) void*)l, 16, 0, 0);
}

// --- merged preprocessing: cvt_w1 | cvt_wcomb | desc | tpose ---------------
// grid.x = 2048 + 6272 + 245 + 4096 = 12661 blocks of 256.
__global__ __launch_bounds__(256) void k_prep(const float* __restrict__ w_conv1,
                                              const float* __restrict__ wcls,
                                              const float* __restrict__ wbbox,
                                              const float* __restrict__ rois,
                                              const float* __restrict__ base_feat,
                                              unsigned short* __restrict__ w1b,
                                              unsigned short* __restrict__ Wc,
                                              int* __restrict__ desc,
                                              unsigned short* __restrict__ featT) {
  __shared__ float tile2[2][64][65];        // used by tpose branch only
  int bid = blockIdx.x;
  if (bid < 2048) {
    // ---- cvt_w1: fp32 [1024][2048] -> bf16 swizzled ----
    int t = bid * 256 + threadIdx.x;
    long e = (long)t * 4;
    int o = (int)(e >> 11), k = (int)(e & 2047);
    float4 q = *(const float4*)(w_conv1 + e);
    short4v s = {(short)f2bf(q.x), (short)f2bf(q.y), (short)f2bf(q.z), (short)f2bf(q.w)};
    int kp = (k & ~63) | swz6(k & 63, o & 7);
    *(short4v*)(w1b + (size_t)o * 2048 + kp) = s;
  } else if (bid < 8320) {
    // ---- cvt_wcomb: Wc[c][ij][k]; c<21 cls, c<105 bbox, else 0 ----
    int t = (bid - 2048) * 256 + threadIdx.x;
    size_t e = (size_t)t * 4;
    int c = (int)(e / 50176);
    int rem = (int)(e - (size_t)c * 50176);
    int ij = rem >> 10, k = rem & 1023;
    float4 q = make_float4(0.f, 0.f, 0.f, 0.f);
    if (c < 21)       q = *(const float4*)(wcls + (size_t)(c * 49 + ij) * 1024 + k);
    else if (c < 105) q = *(const float4*)(wbbox + (size_t)((c - 21) * 49 + ij) * 1024 + k);
    short4v s = {(short)f2bf(q.x), (short)f2bf(q.y), (short)f2bf(q.z), (short)f2bf(q.w)};
    int kp = (k & ~63) | swz6(k & 63, c & 7);
    *(short4v*)(Wc + ((size_t)(c * 49 + ij) * 1024 + kp)) = s;
  } else if (bid < 8565) {
    // ---- desc: per-(roi,bin) descriptors (fp32 ops mirror reference) ----
    int t = (bid - 8320) * 256 + threadIdx.x;
    if (t >= 1280 * 49) return;
    int roi = t / 49, ij = t - roi * 49;
    int* d = desc + (size_t)t * 8;
    if (roi >= 1200) { d[0] = 0; d[1] = 0; d[2] = 0; d[3] = 0; d[4] = 0; ((float*)d)[5] = 0.f; return; }
    const float* r = rois + (size_t)roi * 5;
    int b = (int)r[0];
    float x1 = __fmul_rn(floorf(__fadd_rn(r[1], 0.5f)), 0.0625f);
    float y1 = __fmul_rn(floorf(__fadd_rn(r[2], 0.5f)), 0.0625f);
    float x2 = __fmul_rn(floorf(__fadd_rn(__fadd_rn(r[3], 1.0f), 0.5f)), 0.0625f);
    float y2 = __fmul_rn(floorf(__fadd_rn(__fadd_rn(r[4], 1.0f), 0.5f)), 0.0625f);
    float bw = __fdiv_rn(fmaxf(__fsub_rn(x2, x1), 0.1f), 7.0f);
    float bh = __fdiv_rn(fmaxf(__fsub_rn(y2, y1), 0.1f), 7.0f);
    int i = ij / 7, j = ij - (ij / 7) * 7;
    float fi = (float)i, fj = (float)j;
    int hs = (int)fminf(fmaxf(floorf(__fadd_rn(__fmul_rn(fi, bh), y1)), 0.f), 64.f);
    int he = (int)fminf(fmaxf(ceilf(__fadd_rn(__fmul_rn(__fadd_rn(fi, 1.f), bh), y1)), 0.f), 64.f);
    int wsx = (int)fminf(fmaxf(floorf(__fadd_rn(__fmul_rn(fj, bw), x1)), 0.f), 64.f);
    int we = (int)fminf(fmaxf(ceilf(__fadd_rn(__fmul_rn(__fadd_rn(fj, 1.f), bw), x1)), 0.f), 64.f);
    int dh = max(he - hs, 0), dw = max(we - wsx, 0);
    float inv = (dh * dw > 0) ? 1.0f / (float)(dh * dw) : 0.f;
    d[0] = b; d[1] = hs; d[2] = he; d[3] = wsx; d[4] = we;
    ((float*)d)[5] = inv;
  } else {
    // ---- tpose: base_feat [b][c][s] fp32 -> featT [b][s][c] bf16 swizzled ----
    // two 64x64 s-tiles per block; 8 float4 loads in flight before barrier.
    int t = bid - 8565;                 // 0..4095
    int s0 = (t & 31) * 128;
    int c0 = ((t >> 5) & 31) * 64;
    int b = t >> 10;
    int tx4 = (threadIdx.x & 15) * 4;   // s offset (float4)
    int cl0 = threadIdx.x >> 4;         // 16 c-rows per pass
    const float* sp = base_feat + ((size_t)b * 2048 + c0) * 4096 + s0;
    float4 q[8];
#pragma unroll
    for (int tt = 0; tt < 2; tt++)
#pragma unroll
      for (int i = 0; i < 4; i++) {
        int cl = i * 16 + cl0;
        q[tt * 4 + i] = *(const float4*)(sp + (size_t)cl * 4096 + tt * 64 + tx4);
      }
#pragma unroll
    for (int tt = 0; tt < 2; tt++)
#pragma unroll
      for (int i = 0; i < 4; i++)
        *(float4*)&tile2[tt][i * 16 + cl0][tx4] = q[tt * 4 + i];
    __syncthreads();
    int c8 = (threadIdx.x & 7) * 8;     // 8-channel group (one 16B swizzle unit)
    int sy = threadIdx.x >> 3;          // 0..31 spatial rows per pass
#pragma unroll
    for (int tt = 0; tt < 2; tt++) {
      unsigned short* dp = featT + ((size_t)b * 4096 + s0 + tt * 64) * 2048 + c0;
#pragma unroll
      for (int i = 0; i < 2; i++) {
        int sl = i * 32 + sy;
        int key = sl & 7;
        short8 v = {(short)f2bf(tile2[tt][c8 + 0][sl]), (short)f2bf(tile2[tt][c8 + 1][sl]),
                    (short)f2bf(tile2[tt][c8 + 2][sl]), (short)f2bf(tile2[tt][c8 + 3][sl]),
                    (short)f2bf(tile2[tt][c8 + 4][sl]), (short)f2bf(tile2[tt][c8 + 5][sl]),
                    (short)f2bf(tile2[tt][c8 + 6][sl]), (short)f2bf(tile2[tt][c8 + 7][sl])};
        *(short8*)(dp + (size_t)sl * 2048 + ((((c8 >> 3) ^ key) << 3))) = v;  // 16B store
      }
    }
  }
}

// --- conv1: X[s][o] = relu(sum_k featT[s][k] * w1[o][k]), bf16 out ---------
// 256x256 tile, BK=64, 8 waves (2M x 4N), 9-slot half-tile LDS ring.
__global__ __launch_bounds__(512, 2) void k_gemm_conv1(const short* __restrict__ A,
                                                       const short* __restrict__ Bw,
                                                       unsigned short* __restrict__ X) {
  __shared__ short lds[9 * 8192];   // 9 x 16KB = 144KB ring
  int mt = blockIdx.x, nt = blockIdx.y;
  int tid = threadIdx.x, lane = tid & 63, wave = tid >> 6;
  int wm = wave >> 2, wn = wave & 3;          // 2 x 4 wave grid (128x64 each)

  const short* Ab = A + (size_t)mt * 256 * 2048;
  const short* Bb = Bw + (size_t)nt * 256 * 2048;

  f32x4 acc[8][4];
#pragma unroll
  for (int i = 0; i < 8; i++)
#pragma unroll
    for (int j = 0; j < 4; j++) acc[i][j] = (f32x4){0.f, 0.f, 0.f, 0.f};

  int sr = tid >> 3;                 // staging row 0..63
  int sc = (tid & 7) * 8;            // staging k elem
  auto stage_half = [&](int h) {
    if (h >= 128) return;
    int kind = h & 3, tl = h >> 2, slot = h % 9;
    const short* src = ((kind & 2) ? Bb : Ab)
                     + (size_t)((kind & 1) * 128 + sr) * 2048 + tl * 64 + sc;
    char* dst = (char*)lds + slot * 16384 + tid * 16;
    gload16(src, dst);
    gload16(src + (size_t)64 * 2048, dst + 8192);
  };

  // prologue: stage halves 0..4 (tile 0 fully + Ah0 of tile 1)
#pragma unroll
  for (int h = 0; h < 5; h++) stage_half(h);

  int la15 = lane & 15;
  int key = lane & 7;
  int ko0 = (((lane >> 4)) ^ key) << 3;        // kt=0 fragment k-offset (elems)
  int ko1 = ((4 | (lane >> 4)) ^ key) << 3;    // kt=1
  int bro = (wn & 1) * 64;                     // B local row offset within half

  for (int t = 0; t < 32; ++t) {
    if (t < 31) asm volatile("s_waitcnt vmcnt(2)" ::: "memory");
    else        asm volatile("s_waitcnt vmcnt(0)" ::: "memory");
    __builtin_amdgcn_s_barrier();
    __builtin_amdgcn_sched_barrier(0);
    const short* Asl = lds + (size_t)((4 * t + wm) % 9) * 8192;
    const short* Bsl = lds + (size_t)((4 * t + 2 + (wn >> 1)) % 9) * 8192;
    short8 af[4], bf[4];

    // ---- phase 0: mh=0, kt=0 ----
    stage_half(4 * t + 5);
#pragma unroll
    for (int j = 0; j < 4; j++)
      bf[j] = *(const short8*)(Bsl + (bro + j * 16 + la15) * 64 + ko0);
#pragma unroll
    for (int i = 0; i < 4; i++)
      af[i] = *(const short8*)(Asl + (i * 16 + la15) * 64 + ko0);
    __builtin_amdgcn_s_setprio(1);
#pragma unroll
    for (int i = 0; i < 4; i++)
#pragma unroll
      for (int j = 0; j < 4; j++)
        acc[i][j] = __builtin_amdgcn_mfma_f32_16x16x32_bf16(af[i], bf[j], acc[i][j], 0, 0, 0);
    __builtin_amdgcn_s_setprio(0);

    // ---- phase 1: mh=1, kt=0 ----
    stage_half(4 * t + 6);
#pragma unroll
    for (int i = 0; i < 4; i++)
      af[i] = *(const short8*)(Asl + (64 + i * 16 + la15) * 64 + ko0);
    __builtin_amdgcn_s_setprio(1);
#pragma unroll
    for (int i = 0; i < 4; i++)
#pragma unroll
      for (int j = 0; j < 4; j++)
        acc[4 + i][j] = __builtin_amdgcn_mfma_f32_16x16x32_bf16(af[i], bf[j], acc[4 + i][j], 0, 0, 0);
    __builtin_amdgcn_s_setprio(0);

    // ---- phase 2: mh=0, kt=1 ----
    stage_half(4 * t + 7);
#pragma unroll
    for (int j = 0; j < 4; j++)
      bf[j] = *(const short8*)(Bsl + (bro + j * 16 + la15) * 64 + ko1);
#pragma unroll
    for (int i = 0; i < 4; i++)
      af[i] = *(const short8*)(Asl + (i * 16 + la15) * 64 + ko1);
    __builtin_amdgcn_s_setprio(1);
#pragma unroll
    for (int i = 0; i < 4; i++)
#pragma unroll
      for (int j = 0; j < 4; j++)
        acc[i][j] = __builtin_amdgcn_mfma_f32_16x16x32_bf16(af[i], bf[j], acc[i][j], 0, 0, 0);
    __builtin_amdgcn_s_setprio(0);

    // ---- phase 3: mh=1, kt=1 ----
    stage_half(4 * t + 8);
#pragma unroll
    for (int i = 0; i < 4; i++)
      af[i] = *(const short8*)(Asl + (64 + i * 16 + la15) * 64 + ko1);
    __builtin_amdgcn_s_setprio(1);
#pragma unroll
    for (int i = 0; i < 4; i++)
#pragma unroll
      for (int j = 0; j < 4; j++)
        acc[4 + i][j] = __builtin_amdgcn_mfma_f32_16x16x32_bf16(af[i], bf[j], acc[4 + i][j], 0, 0, 0);
    __builtin_amdgcn_s_setprio(0);
  }

  unsigned short* Xo = X + ((size_t)(mt * 256 + wm * 128)) * 1024 + nt * 256 + wn * 64;
#pragma unroll
  for (int ii = 0; ii < 8; ii++)
#pragma unroll
    for (int j = 0; j < 4; j++) {
      int row = ii * 16 + (lane >> 4) * 4;
      int col = j * 16 + la15;
#pragma unroll
      for (int r = 0; r < 4; r++)
        Xo[(size_t)(row + r) * 1024 + col] = f2bf(fmaxf(acc[ii][j][r], 0.f));
    }
}

// --- fused pool-GEMM (k-split): builds A-tile (bin averages) on the fly ----
// P[kh*49+ij][roi][c] = sum_{k in half kh} mean_bin(X)[roi][ij][k] * Wc[c][ij][k]
// Round-8 body (256t, 2-pass A-build, 3x3 masked batch loads).
// XCD-locality decode: all 98 (ij,kh) blocks of an mt-group share b%8 ->
// same XCD L2 caches that mt's X bin-rows.  Grid 1D = 2352 (some invalid).
__global__ __launch_bounds__(256) void k_fusedpool(const unsigned short* __restrict__ Xb,
                                                   const int* __restrict__ desc,
                                                   const unsigned short* __restrict__ Wc,
                                                   unsigned short* __restrict__ P,
                                                   int nroi) {
  int b0 = blockIdx.x;
  int r = b0 & 7, q = b0 >> 3;
  int mem = q % 98, mtq = q / 98;
  int mt = mtq * 8 + r;        // 64-roi tile
  if (mt >= 20) return;
  int kh = mem & 1;            // k-half 0..1
  int ij = mem >> 1;           // 0..48
  __shared__ short As[64 * 64];    // [roi][k] bf16 (swizzled image)
  __shared__ short Bs[128 * 64];   // [c][k]
  __shared__ int dsc[64][4];       // cellstart, dh, dw, inv-bits
  int tid = threadIdx.x, lane = tid & 63, wave = tid >> 6;

  if (tid < 64) {
    const int* d = desc + ((size_t)(mt * 64 + tid) * 49 + ij) * 8;
    int b = d[0], hs = d[1], he = d[2], wsx = d[3], we = d[4];
    dsc[tid][0] = (b * 64 + hs) * 64 + wsx;   // start cell index
    dsc[tid][1] = max(he - hs, 0);            // dh
    dsc[tid][2] = max(we - wsx, 0);           // dw
    dsc[tid][3] = d[5];                       // inv (float bits)
  }
  __syncthreads();

  f32x4 acc[4][2];
#pragma unroll
  for (int i = 0; i < 4; i++)
#pragma unroll
    for (int j = 0; j < 2; j++) acc[i][j] = (f32x4){0.f, 0.f, 0.f, 0.f};

  const unsigned short* Bb = Wc + (size_t)ij * 1024;
  int lr = lane >> 3, lc = (lane & 7) * 8;
  int key = lane & 7;
  int r8 = tid >> 3;          // 0..31: roi within pass
  int k8 = tid & 7;           // 8-bf16 k-group

  int kbeg = kh * 512, kend = kbeg + 512;
  for (int k0 = kbeg; k0 < kend; k0 += 64) {
    // B staging: async global->LDS (Wc already swizzled in global)
#pragma unroll
    for (int i = 0; i < 4; i++) {
      int row = i * 32 + wave * 8 + lr;
      gload16(Bb + (size_t)row * (49 * 1024) + k0 + lc, (char*)Bs + (i * 32 + wave * 8) * 128);
    }
    // A build: 2 passes x 32 rois.  Per pass: 9 clamped loads issued as a
    // batch (single latency), masked fma accumulate, swizzled 16B LDS store.
#pragma unroll 1
    for (int p = 0; p < 2; p++) {
      int rr = p * 32 + r8;
      int cs = dsc[rr][0], dh = dsc[rr][1], dw = dsc[rr][2];
      float inv = __int_as_float(dsc[rr][3]);
      const unsigned short* xp = Xb + (size_t)cs * 1024 + k0 + k8 * 8;
      float a0 = 0.f, a1 = 0.f, a2 = 0.f, a3 = 0.f;
      float a4 = 0.f, a5 = 0.f, a6 = 0.f, a7 = 0.f;
#pragma unroll
      for (int hh = 0; hh < 3; hh++) {
#pragma unroll
        for (int ww = 0; ww < 3; ww++) {
          int ho = (hh < dh) ? hh : 0;               // clamp -> always valid addr
          int wo = (ww < dw) ? ww : 0;
          float m = ((hh < dh) && (ww < dw)) ? inv : 0.f;
          short8 v = *(const short8*)(xp + (size_t)(ho * 64 + wo) * 1024);
          a0 = fmaf(m, bf2f((unsigned short)v[0]), a0);
          a1 = fmaf(m, bf2f((unsigned short)v[1]), a1);
          a2 = fmaf(m, bf2f((unsigned short)v[2]), a2);
          a3 = fmaf(m, bf2f((unsigned short)v[3]), a3);
          a4 = fmaf(m, bf2f((unsigned short)v[4]), a4);
          a5 = fmaf(m, bf2f((unsigned short)v[5]), a5);
          a6 = fmaf(m, bf2f((unsigned short)v[6]), a6);
          a7 = fmaf(m, bf2f((unsigned short)v[7]), a7);
        }
      }
      short8 o = {(short)f2bf(a0), (short)f2bf(a1), (short)f2bf(a2), (short)f2bf(a3),
                  (short)f2bf(a4), (short)f2bf(a5), (short)f2bf(a6), (short)f2bf(a7)};
      *(short8*)(As + rr * 64 + ((k8 ^ (rr & 7)) << 3)) = o;
    }
    __syncthreads();
#pragma unroll
    for (int kt = 0; kt < 2; kt++) {
      int ko = (((kt << 2) | (lane >> 4)) ^ key) << 3;
      short8 af[4], bfr[2];
#pragma unroll
      for (int i = 0; i < 4; i++)
        af[i] = *(const short8*)(As + (i * 16 + (lane & 15)) * 64 + ko);
#pragma unroll
      for (int j = 0; j < 2; j++)
        bfr[j] = *(const short8*)(Bs + (wave * 32 + j * 16 + (lane & 15)) * 64 + ko);
#pragma unroll
      for (int i = 0; i < 4; i++)
#pragma unroll
        for (int j = 0; j < 2; j++)
          acc[i][j] = __builtin_amdgcn_mfma_f32_16x16x32_bf16(af[i], bfr[j], acc[i][j], 0, 0, 0);
    }
    __syncthreads();
  }
  // store partials P[kh*49+ij][nroi][112] bf16 (c>=112 dropped; only c<105 used)
  unsigned short* Pb = P + (size_t)(kh * 49 + ij) * nroi * 112;
#pragma unroll
  for (int i = 0; i < 4; i++)
#pragma unroll
    for (int j = 0; j < 2; j++) {
      int cc = wave * 32 + j * 16 + (lane & 15);
      if (cc < 112) {
        int rbase = mt * 64 + i * 16 + (lane >> 4) * 4;
#pragma unroll
        for (int rr = 0; rr < 4; rr++)
          Pb[(size_t)(rbase + rr) * 112 + cc] = f2bf(acc[i][j][rr]);
      }
    }
}

// --- reduce 98 partials -> score -> softmax/bbox out (one block per roi) ---
__global__ __launch_bounds__(128) void k_redfinal(const unsigned short* __restrict__ P,
                                                  float* __restrict__ out, int nroi) {
  int roi = blockIdx.x;        // 0..1199
  int c = threadIdx.x;         // 0..127
  __shared__ float sc[112];
  __shared__ float es[32];
  if (c < 112) {
    const unsigned short* p = P + (size_t)roi * 112 + c;
    float s = 0.f;
#pragma unroll 7
    for (int ij = 0; ij < 98; ij++) s += bf2f(p[(size_t)ij * nroi * 112]);
    sc[c] = s * (1.f / 49.f);
  }
  __syncthreads();
  if (c < 21) {
    float mx = -1e30f;
#pragma unroll
    for (int k = 0; k < 21; k++) mx = fmaxf(mx, sc[k]);
    es[c] = expf(sc[c] - mx);
  }
  __syncthreads();
  if (c < 21) {
    float sum = 0.f;
#pragma unroll
    for (int k = 0; k < 21; k++) sum += es[k];
    float rs = 1.f / sum;
    out[(size_t)roi * 21 + c] = es[c] * rs;
  }
  if (c >= 21 && c < 105) {
    out[25200 + (size_t)roi * 84 + (c - 21)] = sc[c];
  }
}

extern "C" void kernel_launch(void* const* d_in, const int* in_sizes, int n_in,
                              void* d_out, int out_size, void* d_ws, size_t ws_size,
                              hipStream_t stream) {
  const float* base_feat = (const float*)d_in[0];
  const float* rois      = (const float*)d_in[1];
  const float* w_conv1   = (const float*)d_in[2];
  const float* w_cls     = (const float*)d_in[3];
  const float* w_bbox    = (const float*)d_in[4];
  float* out = (float*)d_out;
  char* ws = (char*)d_ws;

  unsigned short* featT = (unsigned short*)(ws + OFF_FEATT);
  unsigned short* w1b   = (unsigned short*)(ws + OFF_W1);
  unsigned short* X     = (unsigned short*)(ws + OFF_X);
  unsigned short* Wc    = (unsigned short*)(ws + OFF_WC);
  int*            desc  = (int*)(ws + OFF_DESC);
  unsigned short* P     = (unsigned short*)(ws + OFF_P);

  k_prep<<<12661, 256, 0, stream>>>(w_conv1, w_cls, w_bbox, rois, base_feat,
                                    w1b, Wc, desc, featT);
  k_gemm_conv1<<<dim3(64, 4), 512, 0, stream>>>((const short*)featT, (const short*)w1b, X);
  k_fusedpool<<<2352, 256, 0, stream>>>(X, desc, Wc, P, 1280);
  k_redfinal<<<1200, 128, 0, stream>>>(P, out, 1280);
}

// Round 10
// 354.865 us; speedup vs baseline: 1.0790x; 1.0660x over previous
//
#include <hip/hip_runtime.h>
#include <cstdint>

// ---------------------------------------------------------------------------
// R-FCN head on MI355X.  Round 14 (recovery):
//  - fusedpool: exact round-8 config restored (256t, 2-pass A-build, 3x3
//    masked batch loads, natural dim3(20,49,2) grid).  Round-13's XCD
//    grouping raised FETCH 143->168MB and dur 77->99us (one mt's X set
//    ~4.6MB > 4MB per-XCD L2 -> serialized misses).  Reverted.
//  - prep: tpose blocks dispatch FIRST (bid<4096) -- the latency-bound long
//    pole starts at t=0, cvt/desc backfill.  Decode-only, identical outputs.
//  - conv1 ring pipeline, redfinal unchanged.
//  Round-13: 378.3us.  Predicted ~350us; absmax exactly 0.0006942749.
// ---------------------------------------------------------------------------

typedef __attribute__((ext_vector_type(8))) short short8;   // 8 bf16 (4 VGPRs)
typedef __attribute__((ext_vector_type(4))) short short4v;
typedef __attribute__((ext_vector_type(4))) float f32x4;

// workspace layout (bytes)
#define OFF_FEATT 0ull          // bf16 [4][4096][2048] = 67108864 (dead after conv1)
#define OFF_W1    67108864ull   // bf16 [1024][2048]    = 4194304  (dead after conv1)
#define OFF_X     71303168ull   // bf16 [4][4096][1024] = 33554432 -> ends 104857600
#define OFF_WC    104857600ull  // bf16 [128][49][1024] = 12845056 -> ends 117702656
#define OFF_DESC  117702656ull  // int  [1280][49][8]   = 2007040  -> ends 119709696
#define OFF_P     0ull          // bf16 [98][1280][112] = 28098560 (reuses featT region,
                                //   written only after conv1 has consumed featT)

__device__ __forceinline__ unsigned short f2bf(float f) {
  unsigned u = __float_as_uint(f);
  u += 0x7fffu + ((u >> 16) & 1u);        // round-to-nearest-even
  return (unsigned short)(u >> 16);
}
__device__ __forceinline__ float bf2f(unsigned short h) {
  return __uint_as_float(((unsigned)h) << 16);
}

// swizzle low-6-bits of a k index: 16B group g (bits 3..5) -> g ^ key
__device__ __forceinline__ int swz6(int k6, int key) {
  return ((((k6 >> 3) & 7) ^ key) << 3) | (k6 & 7);
}

__device__ __forceinline__ void gload16(const void* g, void* l) {
  __builtin_amdgcn_global_load_lds((const __attribute__((address_space(1))) void*)g,
                                   (__attribute__((address_space(3))) void*)l, 16, 0, 0);
}

// --- merged preprocessing: tpose | cvt_w1 | cvt_wcomb | desc ---------------
// grid.x = 4096 + 2048 + 6272 + 245 = 12661 blocks of 256.  tpose first.
__global__ __launch_bounds__(256) void k_prep(const float* __restrict__ w_conv1,
                                              const float* __restrict__ wcls,
                                              const float* __restrict__ wbbox,
                                              const float* __restrict__ rois,
                                              const float* __restrict__ base_feat,
                                              unsigned short* __restrict__ w1b,
                                              unsigned short* __restrict__ Wc,
                                              int* __restrict__ desc,
                                              unsigned short* __restrict__ featT) {
  __shared__ float tile2[2][64][65];        // used by tpose branch only
  int bid = blockIdx.x;
  if (bid < 4096) {
    // ---- tpose: base_feat [b][c][s] fp32 -> featT [b][s][c] bf16 swizzled ----
    // two 64x64 s-tiles per block; 8 float4 loads in flight before barrier.
    int t = bid;                        // 0..4095
    int s0 = (t & 31) * 128;
    int c0 = ((t >> 5) & 31) * 64;
    int b = t >> 10;
    int tx4 = (threadIdx.x & 15) * 4;   // s offset (float4)
    int cl0 = threadIdx.x >> 4;         // 16 c-rows per pass
    const float* sp = base_feat + ((size_t)b * 2048 + c0) * 4096 + s0;
    float4 q[8];
#pragma unroll
    for (int tt = 0; tt < 2; tt++)
#pragma unroll
      for (int i = 0; i < 4; i++) {
        int cl = i * 16 + cl0;
        q[tt * 4 + i] = *(const float4*)(sp + (size_t)cl * 4096 + tt * 64 + tx4);
      }
#pragma unroll
    for (int tt = 0; tt < 2; tt++)
#pragma unroll
      for (int i = 0; i < 4; i++)
        *(float4*)&tile2[tt][i * 16 + cl0][tx4] = q[tt * 4 + i];
    __syncthreads();
    int c8 = (threadIdx.x & 7) * 8;     // 8-channel group (one 16B swizzle unit)
    int sy = threadIdx.x >> 3;          // 0..31 spatial rows per pass
#pragma unroll
    for (int tt = 0; tt < 2; tt++) {
      unsigned short* dp = featT + ((size_t)b * 4096 + s0 + tt * 64) * 2048 + c0;
#pragma unroll
      for (int i = 0; i < 2; i++) {
        int sl = i * 32 + sy;
        int key = sl & 7;
        short8 v = {(short)f2bf(tile2[tt][c8 + 0][sl]), (short)f2bf(tile2[tt][c8 + 1][sl]),
                    (short)f2bf(tile2[tt][c8 + 2][sl]), (short)f2bf(tile2[tt][c8 + 3][sl]),
                    (short)f2bf(tile2[tt][c8 + 4][sl]), (short)f2bf(tile2[tt][c8 + 5][sl]),
                    (short)f2bf(tile2[tt][c8 + 6][sl]), (short)f2bf(tile2[tt][c8 + 7][sl])};
        *(short8*)(dp + (size_t)sl * 2048 + ((((c8 >> 3) ^ key) << 3))) = v;  // 16B store
      }
    }
  } else if (bid < 6144) {
    // ---- cvt_w1: fp32 [1024][2048] -> bf16 swizzled ----
    int t = (bid - 4096) * 256 + threadIdx.x;
    long e = (long)t * 4;
    int o = (int)(e >> 11), k = (int)(e & 2047);
    float4 q = *(const float4*)(w_conv1 + e);
    short4v s = {(short)f2bf(q.x), (short)f2bf(q.y), (short)f2bf(q.z), (short)f2bf(q.w)};
    int kp = (k & ~63) | swz6(k & 63, o & 7);
    *(short4v*)(w1b + (size_t)o * 2048 + kp) = s;
  } else if (bid < 12416) {
    // ---- cvt_wcomb: Wc[c][ij][k]; c<21 cls, c<105 bbox, else 0 ----
    int t = (bid - 6144) * 256 + threadIdx.x;
    size_t e = (size_t)t * 4;
    int c = (int)(e / 50176);
    int rem = (int)(e - (size_t)c * 50176);
    int ij = rem >> 10, k = rem & 1023;
    float4 q = make_float4(0.f, 0.f, 0.f, 0.f);
    if (c < 21)       q = *(const float4*)(wcls + (size_t)(c * 49 + ij) * 1024 + k);
    else if (c < 105) q = *(const float4*)(wbbox + (size_t)((c - 21) * 49 + ij) * 1024 + k);
    short4v s = {(short)f2bf(q.x), (short)f2bf(q.y), (short)f2bf(q.z), (short)f2bf(q.w)};
    int kp = (k & ~63) | swz6(k & 63, c & 7);
    *(short4v*)(Wc + ((size_t)(c * 49 + ij) * 1024 + kp)) = s;
  } else {
    // ---- desc: per-(roi,bin) descriptors (fp32 ops mirror reference) ----
    int t = (bid - 12416) * 256 + threadIdx.x;
    if (t >= 1280 * 49) return;
    int roi = t / 49, ij = t - roi * 49;
    int* d = desc + (size_t)t * 8;
    if (roi >= 1200) { d[0] = 0; d[1] = 0; d[2] = 0; d[3] = 0; d[4] = 0; ((float*)d)[5] = 0.f; return; }
    const float* r = rois + (size_t)roi * 5;
    int b = (int)r[0];
    float x1 = __fmul_rn(floorf(__fadd_rn(r[1], 0.5f)), 0.0625f);
    float y1 = __fmul_rn(floorf(__fadd_rn(r[2], 0.5f)), 0.0625f);
    float x2 = __fmul_rn(floorf(__fadd_rn(__fadd_rn(r[3], 1.0f), 0.5f)), 0.0625f);
    float y2 = __fmul_rn(floorf(__fadd_rn(__fadd_rn(r[4], 1.0f), 0.5f)), 0.0625f);
    float bw = __fdiv_rn(fmaxf(__fsub_rn(x2, x1), 0.1f), 7.0f);
    float bh = __fdiv_rn(fmaxf(__fsub_rn(y2, y1), 0.1f), 7.0f);
    int i = ij / 7, j = ij - (ij / 7) * 7;
    float fi = (float)i, fj = (float)j;
    int hs = (int)fminf(fmaxf(floorf(__fadd_rn(__fmul_rn(fi, bh), y1)), 0.f), 64.f);
    int he = (int)fminf(fmaxf(ceilf(__fadd_rn(__fmul_rn(__fadd_rn(fi, 1.f), bh), y1)), 0.f), 64.f);
    int wsx = (int)fminf(fmaxf(floorf(__fadd_rn(__fmul_rn(fj, bw), x1)), 0.f), 64.f);
    int we = (int)fminf(fmaxf(ceilf(__fadd_rn(__fmul_rn(__fadd_rn(fj, 1.f), bw), x1)), 0.f), 64.f);
    int dh = max(he - hs, 0), dw = max(we - wsx, 0);
    float inv = (dh * dw > 0) ? 1.0f / (float)(dh * dw) : 0.f;
    d[0] = b; d[1] = hs; d[2] = he; d[3] = wsx; d[4] = we;
    ((float*)d)[5] = inv;
  }
}

// --- conv1: X[s][o] = relu(sum_k featT[s][k] * w1[o][k]), bf16 out ---------
// 256x256 tile, BK=64, 8 waves (2M x 4N), 9-slot half-tile LDS ring.
__global__ __launch_bounds__(512, 2) void k_gemm_conv1(const short* __restrict__ A,
                                                       const short* __restrict__ Bw,
                                                       unsigned short* __restrict__ X) {
  __shared__ short lds[9 * 8192];   // 9 x 16KB = 144KB ring
  int mt = blockIdx.x, nt = blockIdx.y;
  int tid = threadIdx.x, lane = tid & 63, wave = tid >> 6;
  int wm = wave >> 2, wn = wave & 3;          // 2 x 4 wave grid (128x64 each)

  const short* Ab = A + (size_t)mt * 256 * 2048;
  const short* Bb = Bw + (size_t)nt * 256 * 2048;

  f32x4 acc[8][4];
#pragma unroll
  for (int i = 0; i < 8; i++)
#pragma unroll
    for (int j = 0; j < 4; j++) acc[i][j] = (f32x4){0.f, 0.f, 0.f, 0.f};

  int sr = tid >> 3;                 // staging row 0..63
  int sc = (tid & 7) * 8;            // staging k elem
  auto stage_half = [&](int h) {
    if (h >= 128) return;
    int kind = h & 3, tl = h >> 2, slot = h % 9;
    const short* src = ((kind & 2) ? Bb : Ab)
                     + (size_t)((kind & 1) * 128 + sr) * 2048 + tl * 64 + sc;
    char* dst = (char*)lds + slot * 16384 + tid * 16;
    gload16(src, dst);
    gload16(src + (size_t)64 * 2048, dst + 8192);
  };

  // prologue: stage halves 0..4 (tile 0 fully + Ah0 of tile 1)
#pragma unroll
  for (int h = 0; h < 5; h++) stage_half(h);

  int la15 = lane & 15;
  int key = lane & 7;
  int ko0 = (((lane >> 4)) ^ key) << 3;        // kt=0 fragment k-offset (elems)
  int ko1 = ((4 | (lane >> 4)) ^ key) << 3;    // kt=1
  int bro = (wn & 1) * 64;                     // B local row offset within half

  for (int t = 0; t < 32; ++t) {
    if (t < 31) asm volatile("s_waitcnt vmcnt(2)" ::: "memory");
    else        asm volatile("s_waitcnt vmcnt(0)" ::: "memory");
    __builtin_amdgcn_s_barrier();
    __builtin_amdgcn_sched_barrier(0);
    const short* Asl = lds + (size_t)((4 * t + wm) % 9) * 8192;
    const short* Bsl = lds + (size_t)((4 * t + 2 + (wn >> 1)) % 9) * 8192;
    short8 af[4], bf[4];

    // ---- phase 0: mh=0, kt=0 ----
    stage_half(4 * t + 5);
#pragma unroll
    for (int j = 0; j < 4; j++)
      bf[j] = *(const short8*)(Bsl + (bro + j * 16 + la15) * 64 + ko0);
#pragma unroll
    for (int i = 0; i < 4; i++)
      af[i] = *(const short8*)(Asl + (i * 16 + la15) * 64 + ko0);
    __builtin_amdgcn_s_setprio(1);
#pragma unroll
    for (int i = 0; i < 4; i++)
#pragma unroll
      for (int j = 0; j < 4; j++)
        acc[i][j] = __builtin_amdgcn_mfma_f32_16x16x32_bf16(af[i], bf[j], acc[i][j], 0, 0, 0);
    __builtin_amdgcn_s_setprio(0);

    // ---- phase 1: mh=1, kt=0 ----
    stage_half(4 * t + 6);
#pragma unroll
    for (int i = 0; i < 4; i++)
      af[i] = *(const short8*)(Asl + (64 + i * 16 + la15) * 64 + ko0);
    __builtin_amdgcn_s_setprio(1);
#pragma unroll
    for (int i = 0; i < 4; i++)
#pragma unroll
      for (int j = 0; j < 4; j++)
        acc[4 + i][j] = __builtin_amdgcn_mfma_f32_16x16x32_bf16(af[i], bf[j], acc[4 + i][j], 0, 0, 0);
    __builtin_amdgcn_s_setprio(0);

    // ---- phase 2: mh=0, kt=1 ----
    stage_half(4 * t + 7);
#pragma unroll
    for (int j = 0; j < 4; j++)
      bf[j] = *(const short8*)(Bsl + (bro + j * 16 + la15) * 64 + ko1);
#pragma unroll
    for (int i = 0; i < 4; i++)
      af[i] = *(const short8*)(Asl + (i * 16 + la15) * 64 + ko1);
    __builtin_amdgcn_s_setprio(1);
#pragma unroll
    for (int i = 0; i < 4; i++)
#pragma unroll
      for (int j = 0; j < 4; j++)
        acc[i][j] = __builtin_amdgcn_mfma_f32_16x16x32_bf16(af[i], bf[j], acc[i][j], 0, 0, 0);
    __builtin_amdgcn_s_setprio(0);

    // ---- phase 3: mh=1, kt=1 ----
    stage_half(4 * t + 8);
#pragma unroll
    for (int i = 0; i < 4; i++)
      af[i] = *(const short8*)(Asl + (64 + i * 16 + la15) * 64 + ko1);
    __builtin_amdgcn_s_setprio(1);
#pragma unroll
    for (int i = 0; i < 4; i++)
#pragma unroll
      for (int j = 0; j < 4; j++)
        acc[4 + i][j] = __builtin_amdgcn_mfma_f32_16x16x32_bf16(af[i], bf[j], acc[4 + i][j], 0, 0, 0);
    __builtin_amdgcn_s_setprio(0);
  }

  unsigned short* Xo = X + ((size_t)(mt * 256 + wm * 128)) * 1024 + nt * 256 + wn * 64;
#pragma unroll
  for (int ii = 0; ii < 8; ii++)
#pragma unroll
    for (int j = 0; j < 4; j++) {
      int row = ii * 16 + (lane >> 4) * 4;
      int col = j * 16 + la15;
#pragma unroll
      for (int r = 0; r < 4; r++)
        Xo[(size_t)(row + r) * 1024 + col] = f2bf(fmaxf(acc[ii][j][r], 0.f));
    }
}

// --- fused pool-GEMM (k-split): builds A-tile (bin averages) on the fly ----
// P[kh*49+ij][roi][c] = sum_{k in half kh} mean_bin(X)[roi][ij][k] * Wc[c][ij][k]
// Round-8 config: 256t, 2-pass A-build, 3x3 masked batch loads, natural grid.
__global__ __launch_bounds__(256) void k_fusedpool(const unsigned short* __restrict__ Xb,
                                                   const int* __restrict__ desc,
                                                   const unsigned short* __restrict__ Wc,
                                                   unsigned short* __restrict__ P,
                                                   int nroi) {
  int mt = blockIdx.x;   // 64-roi tile
  int ij = blockIdx.y;   // 0..48
  int kh = blockIdx.z;   // k-half 0..1
  __shared__ short As[64 * 64];    // [roi][k] bf16 (swizzled image)
  __shared__ short Bs[128 * 64];   // [c][k]
  __shared__ int dsc[64][4];       // cellstart, dh, dw, inv-bits
  int tid = threadIdx.x, lane = tid & 63, wave = tid >> 6;

  if (tid < 64) {
    const int* d = desc + ((size_t)(mt * 64 + tid) * 49 + ij) * 8;
    int b = d[0], hs = d[1], he = d[2], wsx = d[3], we = d[4];
    dsc[tid][0] = (b * 64 + hs) * 64 + wsx;   // start cell index
    dsc[tid][1] = max(he - hs, 0);            // dh
    dsc[tid][2] = max(we - wsx, 0);           // dw
    dsc[tid][3] = d[5];                       // inv (float bits)
  }
  __syncthreads();

  f32x4 acc[4][2];
#pragma unroll
  for (int i = 0; i < 4; i++)
#pragma unroll
    for (int j = 0; j < 2; j++) acc[i][j] = (f32x4){0.f, 0.f, 0.f, 0.f};

  const unsigned short* Bb = Wc + (size_t)ij * 1024;
  int lr = lane >> 3, lc = (lane & 7) * 8;
  int key = lane & 7;
  int r8 = tid >> 3;          // 0..31: roi within pass
  int k8 = tid & 7;           // 8-bf16 k-group

  int kbeg = kh * 512, kend = kbeg + 512;
  for (int k0 = kbeg; k0 < kend; k0 += 64) {
    // B staging: async global->LDS (Wc already swizzled in global)
#pragma unroll
    for (int i = 0; i < 4; i++) {
      int row = i * 32 + wave * 8 + lr;
      gload16(Bb + (size_t)row * (49 * 1024) + k0 + lc, (char*)Bs + (i * 32 + wave * 8) * 128);
    }
    // A build: 2 passes x 32 rois.  Per pass: 9 clamped loads issued as a
    // batch (single latency), masked fma accumulate, swizzled 16B LDS store.
#pragma unroll 1
    for (int p = 0; p < 2; p++) {
      int rr = p * 32 + r8;
      int cs = dsc[rr][0], dh = dsc[rr][1], dw = dsc[rr][2];
      float inv = __int_as_float(dsc[rr][3]);
      const unsigned short* xp = Xb + (size_t)cs * 1024 + k0 + k8 * 8;
      float a0 = 0.f, a1 = 0.f, a2 = 0.f, a3 = 0.f;
      float a4 = 0.f, a5 = 0.f, a6 = 0.f, a7 = 0.f;
#pragma unroll
      for (int hh = 0; hh < 3; hh++) {
#pragma unroll
        for (int ww = 0; ww < 3; ww++) {
          int ho = (hh < dh) ? hh : 0;               // clamp -> always valid addr
          int wo = (ww < dw) ? ww : 0;
          float m = ((hh < dh) && (ww < dw)) ? inv : 0.f;
          short8 v = *(const short8*)(xp + (size_t)(ho * 64 + wo) * 1024);
          a0 = fmaf(m, bf2f((unsigned short)v[0]), a0);
          a1 = fmaf(m, bf2f((unsigned short)v[1]), a1);
          a2 = fmaf(m, bf2f((unsigned short)v[2]), a2);
          a3 = fmaf(m, bf2f((unsigned short)v[3]), a3);
          a4 = fmaf(m, bf2f((unsigned short)v[4]), a4);
          a5 = fmaf(m, bf2f((unsigned short)v[5]), a5);
          a6 = fmaf(m, bf2f((unsigned short)v[6]), a6);
          a7 = fmaf(m, bf2f((unsigned short)v[7]), a7);
        }
      }
      short8 o = {(short)f2bf(a0), (short)f2bf(a1), (short)f2bf(a2), (short)f2bf(a3),
                  (short)f2bf(a4), (short)f2bf(a5), (short)f2bf(a6), (short)f2bf(a7)};
      *(short8*)(As + rr * 64 + ((k8 ^ (rr & 7)) << 3)) = o;
    }
    __syncthreads();
#pragma unroll
    for (int kt = 0; kt < 2; kt++) {
      int ko = (((kt << 2) | (lane >> 4)) ^ key) << 3;
      short8 af[4], bfr[2];
#pragma unroll
      for (int i = 0; i < 4; i++)
        af[i] = *(const short8*)(As + (i * 16 + (lane & 15)) * 64 + ko);
#pragma unroll
      for (int j = 0; j < 2; j++)
        bfr[j] = *(const short8*)(Bs + (wave * 32 + j * 16 + (lane & 15)) * 64 + ko);
#pragma unroll
      for (int i = 0; i < 4; i++)
#pragma unroll
        for (int j = 0; j < 2; j++)
          acc[i][j] = __builtin_amdgcn_mfma_f32_16x16x32_bf16(af[i], bfr[j], acc[i][j], 0, 0, 0);
    }
    __syncthreads();
  }
  // store partials P[kh*49+ij][nroi][112] bf16 (c>=112 dropped; only c<105 used)
  unsigned short* Pb = P + (size_t)(kh * 49 + ij) * nroi * 112;
#pragma unroll
  for (int i = 0; i < 4; i++)
#pragma unroll
    for (int j = 0; j < 2; j++) {
      int cc = wave * 32 + j * 16 + (lane & 15);
      if (cc < 112) {
        int rbase = mt * 64 + i * 16 + (lane >> 4) * 4;
#pragma unroll
        for (int rr = 0; rr < 4; rr++)
          Pb[(size_t)(rbase + rr) * 112 + cc] = f2bf(acc[i][j][rr]);
      }
    }
}

// --- reduce 98 partials -> score -> softmax/bbox out (one block per roi) ---
__global__ __launch_bounds__(128) void k_redfinal(const unsigned short* __restrict__ P,
                                                  float* __restrict__ out, int nroi) {
  int roi = blockIdx.x;        // 0..1199
  int c = threadIdx.x;         // 0..127
  __shared__ float sc[112];
  __shared__ float es[32];
  if (c < 112) {
    const unsigned short* p = P + (size_t)roi * 112 + c;
    float s = 0.f;
#pragma unroll 7
    for (int ij = 0; ij < 98; ij++) s += bf2f(p[(size_t)ij * nroi * 112]);
    sc[c] = s * (1.f / 49.f);
  }
  __syncthreads();
  if (c < 21) {
    float mx = -1e30f;
#pragma unroll
    for (int k = 0; k < 21; k++) mx = fmaxf(mx, sc[k]);
    es[c] = expf(sc[c] - mx);
  }
  __syncthreads();
  if (c < 21) {
    float sum = 0.f;
#pragma unroll
    for (int k = 0; k < 21; k++) sum += es[k];
    float rs = 1.f / sum;
    out[(size_t)roi * 21 + c] = es[c] * rs;
  }
  if (c >= 21 && c < 105) {
    out[25200 + (size_t)roi * 84 + (c - 21)] = sc[c];
  }
}

extern "C" void kernel_launch(void* const* d_in, const int* in_sizes, int n_in,
                              void* d_out, int out_size, void* d_ws, size_t ws_size,
                              hipStream_t stream) {
  const float* base_feat = (const float*)d_in[0];
  const float* rois      = (const float*)d_in[1];
  const float* w_conv1   = (const float*)d_in[2];
  const float* w_cls     = (const float*)d_in[3];
  const float* w_bbox    = (const float*)d_in[4];
  float* out = (float*)d_out;
  char* ws = (char*)d_ws;

  unsigned short* featT = (unsigned short*)(ws + OFF_FEATT);
  unsigned short* w1b   = (unsigned short*)(ws + OFF_W1);
  unsigned short* X     = (unsigned short*)(ws + OFF_X);
  unsigned short* Wc    = (unsigned short*)(ws + OFF_WC);
  int*            desc  = (int*)(ws + OFF_DESC);
  unsigned short* P     = (unsigned short*)(ws + OFF_P);

  k_prep<<<12661, 256, 0, stream>>>(w_conv1, w_cls, w_bbox, rois, base_feat,
                                    w1b, Wc, desc, featT);
  k_gemm_conv1<<<dim3(64, 4), 512, 0, stream>>>((const short*)featT, (const short*)w1b, X);
  k_fusedpool<<<dim3(20, 49, 2), 256, 0, stream>>>(X, desc, Wc, P, 1280);
  k_redfinal<<<1200, 128, 0, stream>>>(P, out, 1280);
}